// Round 3
// baseline (89.620 us; speedup 1.0000x reference)
//
#include <hip/hip_runtime.h>
#include <hip/hip_bf16.h>

#define TWO_N 8192
#define NHALF 4096
#define D 256
static constexpr float INV_T = 2.0f; // 1 / 0.5

typedef __attribute__((ext_vector_type(8))) short short8;
typedef __attribute__((ext_vector_type(4))) float f32x4;

#define AS1 __attribute__((address_space(1)))
#define AS3 __attribute__((address_space(3)))

__device__ __forceinline__ float bfu2f(ushort u) {
    unsigned int x = ((unsigned int)u) << 16;
    return __uint_as_float(x);
}
__device__ __forceinline__ ushort f2bfu(float f) {
    __hip_bfloat16 b = __float2bfloat16(f);
    return *reinterpret_cast<ushort*>(&b);
}

// ---------------- kernel 1: row-normalize to bf16, zero denom ----------------
// one wave per row; float4 loads (16B/lane), ushort4 stores (8B/lane)
__global__ __launch_bounds__(256) void normalize_kernel(
        const float* __restrict__ z_i, const float* __restrict__ z_j,
        ushort* __restrict__ zn, float* __restrict__ denom) {
    const int wid = threadIdx.x >> 6, lane = threadIdx.x & 63;
    const int row = blockIdx.x * 4 + wid;
    const float* src = (row < NHALF) ? (z_i + (size_t)row * D)
                                     : (z_j + (size_t)(row - NHALF) * D);
    const float4 v = *reinterpret_cast<const float4*>(src + lane * 4);
    float ss = v.x * v.x + v.y * v.y + v.z * v.z + v.w * v.w;
    #pragma unroll
    for (int off = 32; off; off >>= 1) ss += __shfl_xor(ss, off);
    const float rn = rsqrtf(ss);
    ushort4 o;
    o.x = f2bfu(v.x * rn); o.y = f2bfu(v.y * rn);
    o.z = f2bfu(v.z * rn); o.w = f2bfu(v.w * rn);
    *reinterpret_cast<ushort4*>(zn + (size_t)row * D + lane * 4) = o;
    if (lane == 0) denom[row] = 0.0f;
}

// ---------------- kernel 2: positive-pair similarity ----------------
__global__ __launch_bounds__(256) void pos_kernel(
        const ushort* __restrict__ zn, float* __restrict__ sim_pos) {
    const int wid = threadIdx.x >> 6, lane = threadIdx.x & 63;
    const int i = blockIdx.x * 4 + wid;
    const int p = (i + NHALF) & (TWO_N - 1);
    const ushort4 va = *reinterpret_cast<const ushort4*>(zn + (size_t)i * D + lane * 4);
    const ushort4 vb = *reinterpret_cast<const ushort4*>(zn + (size_t)p * D + lane * 4);
    float s = bfu2f(va.x) * bfu2f(vb.x) + bfu2f(va.y) * bfu2f(vb.y)
            + bfu2f(va.z) * bfu2f(vb.z) + bfu2f(va.w) * bfu2f(vb.w);
    #pragma unroll
    for (int off = 32; off; off >>= 1) s += __shfl_xor(s, off);
    if (lane == 0) sim_pos[i] = s * INV_T;
}

// ---------------- kernel 3: fused symmetric sim-GEMM + exp + row/col sums ----
// BM=BN=128, 4 waves (2x2), per-wave 64x64 output, mfma_f32_16x16x32_bf16.
// A-tile staged for the FULL K=256 once per block (64 KB LDS, K-major layout);
// B double-buffered in BK=32 steps (2 x 8 KB). One barrier per K-step.
// K-major slot layout (slot = kchunk*128 + row, 16B/slot): ds_read_b128 banks
// balanced by construction (bank group = row&7, 8 lanes/group), and
// global_load_lds destinations stay linear.
// Symmetry: tiles tc>=tr only; off-diag tiles add row sums to denom[r] and
// col sums to denom[c]; diagonal tiles zero r==c exactly.
__global__ __launch_bounds__(256) void gemm_denom_kernel(
        const ushort* __restrict__ zn, float* __restrict__ denom) {
    const int tr = blockIdx.x;
    const int tc = blockIdx.y;
    if (tc < tr) return;  // block-uniform exit before any sync

    __shared__ ushort As[32 * 128 * 8];    // 64 KB: A, full K
    __shared__ ushort Bs[2][4 * 128 * 8];  // 2 x 8 KB: B, BK=32 double-buffered

    const int tid  = threadIdx.x;
    const int lane = tid & 63;
    const int wid  = tid >> 6;
    const int wr   = wid >> 1;
    const int wc   = wid & 1;
    const int r16  = lane & 15;
    const int kgrp = lane >> 4;
    const int row0 = tr * 128;
    const int col0 = tc * 128;

    // ---- prologue: stage A (full K) + B step 0 ----
    #pragma unroll
    for (int it = 0; it < 16; ++it) {
        const int s = it * 256 + tid;          // slot 0..4095
        const int c = s >> 7, r = s & 127;     // kchunk, row
        const ushort* ga = zn + (size_t)(row0 + r) * D + c * 8;
        __builtin_amdgcn_global_load_lds((const AS1 void*)ga,
            (AS3 void*)(As + (it * 256 + wid * 64) * 8), 16, 0, 0);
    }
    #pragma unroll
    for (int it = 0; it < 2; ++it) {
        const int s = it * 256 + tid;          // slot 0..511
        const int c = s >> 7, r = s & 127;
        const ushort* gb = zn + (size_t)(col0 + r) * D + c * 8;
        __builtin_amdgcn_global_load_lds((const AS1 void*)gb,
            (AS3 void*)(Bs[0] + (it * 256 + wid * 64) * 8), 16, 0, 0);
    }

    f32x4 acc[4][4];
    #pragma unroll
    for (int m = 0; m < 4; ++m)
        #pragma unroll
        for (int n = 0; n < 4; ++n) {
            f32x4 z = {0.f, 0.f, 0.f, 0.f};
            acc[m][n] = z;
        }

    #pragma unroll
    for (int ks = 0; ks < 8; ++ks) {
        const int cur = ks & 1;
        __syncthreads();  // vmcnt(0): stage done; lgkmcnt: prior reads done
        if (ks < 7) {
            #pragma unroll
            for (int it = 0; it < 2; ++it) {
                const int s = it * 256 + tid;
                const int c = s >> 7, r = s & 127;
                const ushort* gb = zn + (size_t)(col0 + r) * D + (ks + 1) * 32 + c * 8;
                __builtin_amdgcn_global_load_lds((const AS1 void*)gb,
                    (AS3 void*)(Bs[cur ^ 1] + (it * 256 + wid * 64) * 8), 16, 0, 0);
            }
        }
        short8 a[4], b[4];
        #pragma unroll
        for (int m = 0; m < 4; ++m)
            a[m] = *reinterpret_cast<const short8*>(
                As + (((ks * 4 + kgrp) * 128) + wr * 64 + m * 16 + r16) * 8);
        #pragma unroll
        for (int n = 0; n < 4; ++n)
            b[n] = *reinterpret_cast<const short8*>(
                Bs[cur] + ((kgrp * 128) + wc * 64 + n * 16 + r16) * 8);
        #pragma unroll
        for (int m = 0; m < 4; ++m)
            #pragma unroll
            for (int n = 0; n < 4; ++n)
                acc[m][n] = __builtin_amdgcn_mfma_f32_16x16x32_bf16(
                    a[m], b[n], acc[m][n], 0, 0, 0);
    }

    // ---- epilogue: exp, diag zero, row sums (+ col sums if off-diagonal) ----
    const bool offdiag = (tr != tc);
    float cs[4] = {0.f, 0.f, 0.f, 0.f};
    #pragma unroll
    for (int m = 0; m < 4; ++m) {
        #pragma unroll
        for (int reg = 0; reg < 4; ++reg) {
            const int rg = row0 + wr * 64 + m * 16 + kgrp * 4 + reg;
            float rs = 0.f;
            #pragma unroll
            for (int n = 0; n < 4; ++n) {
                const int cg = col0 + wc * 64 + n * 16 + r16;
                float e = __expf(acc[m][n][reg] * INV_T);
                if (rg == cg) e = 0.f;   // only possible when tr==tc
                rs += e;
                cs[n] += e;
            }
            rs += __shfl_xor(rs, 1);
            rs += __shfl_xor(rs, 2);
            rs += __shfl_xor(rs, 4);
            rs += __shfl_xor(rs, 8);
            if (r16 == 0) atomicAdd(&denom[rg], rs);
        }
    }
    if (offdiag) {
        #pragma unroll
        for (int n = 0; n < 4; ++n) {
            cs[n] += __shfl_xor(cs[n], 16);
            cs[n] += __shfl_xor(cs[n], 32);
        }
        if (kgrp == 0) {
            #pragma unroll
            for (int n = 0; n < 4; ++n)
                atomicAdd(&denom[col0 + wc * 64 + n * 16 + r16], cs[n]);
        }
    }
}

// ---------------- kernel 4: final loss reduction ----------------
__global__ __launch_bounds__(1024) void final_kernel(
        const float* __restrict__ sim_pos, const float* __restrict__ denom,
        float* __restrict__ out) {
    const int tid = threadIdx.x;
    float s = 0.f;
    for (int i = tid; i < TWO_N; i += 1024)
        s += sim_pos[i] - logf(denom[i]);
    #pragma unroll
    for (int off = 32; off; off >>= 1) s += __shfl_down(s, off);
    __shared__ float red[16];
    const int wid = tid >> 6, lane = tid & 63;
    if (lane == 0) red[wid] = s;
    __syncthreads();
    if (tid == 0) {
        float t = 0.f;
        #pragma unroll
        for (int w = 0; w < 16; ++w) t += red[w];
        out[0] = -t / (float)TWO_N;
    }
}

extern "C" void kernel_launch(void* const* d_in, const int* in_sizes, int n_in,
                              void* d_out, int out_size, void* d_ws, size_t ws_size,
                              hipStream_t stream) {
    const float* z_i = (const float*)d_in[0];
    const float* z_j = (const float*)d_in[1];
    float* out = (float*)d_out;

    ushort* zn      = (ushort*)d_ws;                                  // 4 MB
    float*  sim_pos = (float*)((char*)d_ws + (size_t)TWO_N * D * 2);  // 32 KB
    float*  denom   = sim_pos + TWO_N;                                // 32 KB

    normalize_kernel<<<TWO_N / 4, 256, 0, stream>>>(z_i, z_j, zn, denom);
    pos_kernel<<<TWO_N / 4, 256, 0, stream>>>(zn, sim_pos);
    dim3 grid(TWO_N / 128, TWO_N / 128);
    gemm_denom_kernel<<<grid, 256, 0, stream>>>(zn, denom);
    final_kernel<<<1, 1024, 0, stream>>>(sim_pos, denom, out);
}

// Round 5
// 84.452 us; speedup vs baseline: 1.0612x; 1.0612x over previous
//
#include <hip/hip_runtime.h>
#include <hip/hip_bf16.h>

#define TWO_N 8192
#define NHALF 4096
#define D 256
#define NTILE 64   // 8192 / 128 tiles per dimension
static constexpr float INV_T = 2.0f; // 1 / 0.5

typedef __attribute__((ext_vector_type(8))) short short8;
typedef __attribute__((ext_vector_type(4))) float f32x4;

#define AS1 __attribute__((address_space(1)))
#define AS3 __attribute__((address_space(3)))

__device__ __forceinline__ float bfu2f(ushort u) {
    unsigned int x = ((unsigned int)u) << 16;
    return __uint_as_float(x);
}
__device__ __forceinline__ ushort f2bfu(float f) {
    __hip_bfloat16 b = __float2bfloat16(f);
    return *reinterpret_cast<ushort*>(&b);
}

// ------ kernel 1: fused normalize (both halves) + positive-pair sim ------
__global__ __launch_bounds__(256) void norm_pos_kernel(
        const float* __restrict__ z_i, const float* __restrict__ z_j,
        ushort* __restrict__ zn, float* __restrict__ sim_pos,
        float* __restrict__ denom) {
    const int wid = threadIdx.x >> 6, lane = threadIdx.x & 63;
    const int i = blockIdx.x * 4 + wid;  // 0..4095
    const float4 vi = *reinterpret_cast<const float4*>(z_i + (size_t)i * D + lane * 4);
    const float4 vj = *reinterpret_cast<const float4*>(z_j + (size_t)i * D + lane * 4);
    float ssi = vi.x * vi.x + vi.y * vi.y + vi.z * vi.z + vi.w * vi.w;
    float ssj = vj.x * vj.x + vj.y * vj.y + vj.z * vj.z + vj.w * vj.w;
    float dt  = vi.x * vj.x + vi.y * vj.y + vi.z * vj.z + vi.w * vj.w;
    #pragma unroll
    for (int off = 32; off; off >>= 1) {
        ssi += __shfl_xor(ssi, off);
        ssj += __shfl_xor(ssj, off);
        dt  += __shfl_xor(dt,  off);
    }
    const float ri = rsqrtf(ssi), rj = rsqrtf(ssj);
    ushort4 oi, oj;
    oi.x = f2bfu(vi.x * ri); oi.y = f2bfu(vi.y * ri);
    oi.z = f2bfu(vi.z * ri); oi.w = f2bfu(vi.w * ri);
    oj.x = f2bfu(vj.x * rj); oj.y = f2bfu(vj.y * rj);
    oj.z = f2bfu(vj.z * rj); oj.w = f2bfu(vj.w * rj);
    *reinterpret_cast<ushort4*>(zn + (size_t)i * D + lane * 4) = oi;
    *reinterpret_cast<ushort4*>(zn + (size_t)(i + NHALF) * D + lane * 4) = oj;
    if (lane == 0) {
        const float sp = dt * ri * rj * INV_T;
        sim_pos[i] = sp;
        sim_pos[i + NHALF] = sp;   // symmetric
        denom[i] = 0.0f;
        denom[i + NHALF] = 0.0f;
    }
}

// ------ kernel 2: fused symmetric sim-GEMM + exp + row/col sums ------
// BM=BN=128, BK=32, 4 waves (2x2), per-wave 64x64, mfma_f32_16x16x32_bf16.
// A and B both double-buffered (4 x 8 KB LDS = 32 KB). 2-phase schedule:
//   STAGE(next) -> ds_read+MFMA(cur) -> __syncthreads()
// K-major slot layout (slot = kchunk*128 + row, 16B slots): conflict-free
// ds_read_b128 (verified 0 conflicts in R3) + linear global_load_lds dests.
// Compact 1D grid over the 2080 upper-triangle tiles of the 64x64 tile grid.
__global__ __launch_bounds__(256) void gemm_denom_kernel(
        const ushort* __restrict__ zn, float* __restrict__ denom) {
    // bid -> (tr, tc), tc >= tr, NTILE x NTILE tile grid
    // (R4 bug: used 32 here with a 64-wide grid -> infinite loop. NTILE=64.)
    int rem = blockIdx.x;
    int tr = 0;
    while (rem >= NTILE - tr) { rem -= NTILE - tr; ++tr; }
    const int tc = tr + rem;

    __shared__ ushort As[2][4 * 128 * 8];  // 2 x 8 KB
    __shared__ ushort Bs[2][4 * 128 * 8];  // 2 x 8 KB

    const int tid  = threadIdx.x;
    const int lane = tid & 63;
    const int wid  = tid >> 6;
    const int wr   = wid >> 1;
    const int wc   = wid & 1;
    const int r16  = lane & 15;
    const int kgrp = lane >> 4;
    const int row0 = tr * 128;
    const int col0 = tc * 128;

    // per-thread staging slots: s = it*256+tid, kchunk = s>>7, row = s&127
    const int s0 = tid, s1 = 256 + tid;
    const int r0s = s0 & 127, c0s = (s0 >> 7) * 8;
    const int r1s = s1 & 127, c1s = (s1 >> 7) * 8;
    const ushort* gA0 = zn + (size_t)(row0 + r0s) * D + c0s;
    const ushort* gA1 = zn + (size_t)(row0 + r1s) * D + c1s;
    const ushort* gB0 = zn + (size_t)(col0 + r0s) * D + c0s;
    const ushort* gB1 = zn + (size_t)(col0 + r1s) * D + c1s;
    const int d0 = (0 * 256 + wid * 64) * 8;   // LDS dest offsets (ushort units)
    const int d1 = (1 * 256 + wid * 64) * 8;

    #define STAGE(buf, k0)                                                        \
        do {                                                                      \
            __builtin_amdgcn_global_load_lds((const AS1 void*)(gA0 + (k0)),       \
                (AS3 void*)(As[buf] + d0), 16, 0, 0);                             \
            __builtin_amdgcn_global_load_lds((const AS1 void*)(gA1 + (k0)),       \
                (AS3 void*)(As[buf] + d1), 16, 0, 0);                             \
            __builtin_amdgcn_global_load_lds((const AS1 void*)(gB0 + (k0)),       \
                (AS3 void*)(Bs[buf] + d0), 16, 0, 0);                             \
            __builtin_amdgcn_global_load_lds((const AS1 void*)(gB1 + (k0)),       \
                (AS3 void*)(Bs[buf] + d1), 16, 0, 0);                             \
        } while (0)

    f32x4 acc[4][4];
    #pragma unroll
    for (int m = 0; m < 4; ++m)
        #pragma unroll
        for (int n = 0; n < 4; ++n) {
            f32x4 z = {0.f, 0.f, 0.f, 0.f};
            acc[m][n] = z;
        }

    STAGE(0, 0);
    __syncthreads();

    #pragma unroll
    for (int ks = 0; ks < 8; ++ks) {
        const int cur = ks & 1;
        if (ks < 7) STAGE(cur ^ 1, (ks + 1) * 32);
        short8 a[4], b[4];
        #pragma unroll
        for (int m = 0; m < 4; ++m)
            a[m] = *reinterpret_cast<const short8*>(
                As[cur] + ((kgrp * 128) + wr * 64 + m * 16 + r16) * 8);
        #pragma unroll
        for (int n = 0; n < 4; ++n)
            b[n] = *reinterpret_cast<const short8*>(
                Bs[cur] + ((kgrp * 128) + wc * 64 + n * 16 + r16) * 8);
        #pragma unroll
        for (int m = 0; m < 4; ++m)
            #pragma unroll
            for (int n = 0; n < 4; ++n)
                acc[m][n] = __builtin_amdgcn_mfma_f32_16x16x32_bf16(
                    a[m], b[n], acc[m][n], 0, 0, 0);
        if (ks < 7) __syncthreads();
    }
    #undef STAGE

    // ---- epilogue: exp, diag zero, row sums (+ col sums if off-diagonal) ----
    const bool offdiag = (tr != tc);
    float cs[4] = {0.f, 0.f, 0.f, 0.f};
    #pragma unroll
    for (int m = 0; m < 4; ++m) {
        #pragma unroll
        for (int reg = 0; reg < 4; ++reg) {
            const int rg = row0 + wr * 64 + m * 16 + kgrp * 4 + reg;
            float rs = 0.f;
            #pragma unroll
            for (int n = 0; n < 4; ++n) {
                const int cg = col0 + wc * 64 + n * 16 + r16;
                float e = __expf(acc[m][n][reg] * INV_T);
                if (rg == cg) e = 0.f;   // only possible when tr==tc
                rs += e;
                cs[n] += e;
            }
            rs += __shfl_xor(rs, 1);
            rs += __shfl_xor(rs, 2);
            rs += __shfl_xor(rs, 4);
            rs += __shfl_xor(rs, 8);
            if (r16 == 0) atomicAdd(&denom[rg], rs);
        }
    }
    if (offdiag) {
        #pragma unroll
        for (int n = 0; n < 4; ++n) {
            cs[n] += __shfl_xor(cs[n], 16);
            cs[n] += __shfl_xor(cs[n], 32);
        }
        if (kgrp == 0) {
            #pragma unroll
            for (int n = 0; n < 4; ++n)
                atomicAdd(&denom[col0 + wc * 64 + n * 16 + r16], cs[n]);
        }
    }
}

// ---------------- kernel 3: final loss reduction ----------------
__global__ __launch_bounds__(1024) void final_kernel(
        const float* __restrict__ sim_pos, const float* __restrict__ denom,
        float* __restrict__ out) {
    const int tid = threadIdx.x;
    float s = 0.f;
    for (int i = tid; i < TWO_N; i += 1024)
        s += sim_pos[i] - logf(denom[i]);
    #pragma unroll
    for (int off = 32; off; off >>= 1) s += __shfl_down(s, off);
    __shared__ float red[16];
    const int wid = tid >> 6, lane = tid & 63;
    if (lane == 0) red[wid] = s;
    __syncthreads();
    if (tid == 0) {
        float t = 0.f;
        #pragma unroll
        for (int w = 0; w < 16; ++w) t += red[w];
        out[0] = -t / (float)TWO_N;
    }
}

extern "C" void kernel_launch(void* const* d_in, const int* in_sizes, int n_in,
                              void* d_out, int out_size, void* d_ws, size_t ws_size,
                              hipStream_t stream) {
    const float* z_i = (const float*)d_in[0];
    const float* z_j = (const float*)d_in[1];
    float* out = (float*)d_out;

    ushort* zn      = (ushort*)d_ws;                                  // 4 MB
    float*  sim_pos = (float*)((char*)d_ws + (size_t)TWO_N * D * 2);  // 32 KB
    float*  denom   = sim_pos + TWO_N;                                // 32 KB

    norm_pos_kernel<<<NHALF / 4, 256, 0, stream>>>(z_i, z_j, zn, sim_pos, denom);
    gemm_denom_kernel<<<NTILE * (NTILE + 1) / 2, 256, 0, stream>>>(zn, denom);
    final_kernel<<<1, 1024, 0, stream>>>(sim_pos, denom, out);
}

// Round 6
// 80.860 us; speedup vs baseline: 1.1083x; 1.0444x over previous
//
#include <hip/hip_runtime.h>
#include <hip/hip_bf16.h>

#define TWO_N 8192
#define NHALF 4096
#define D 256
#define NTILE 64   // 8192 / 128 tiles per dimension
static constexpr float INV_T = 2.0f; // 1 / 0.5

typedef __attribute__((ext_vector_type(8))) short short8;
typedef __attribute__((ext_vector_type(4))) float f32x4;

#define AS1 __attribute__((address_space(1)))
#define AS3 __attribute__((address_space(3)))

__device__ __forceinline__ float bfu2f(ushort u) {
    unsigned int x = ((unsigned int)u) << 16;
    return __uint_as_float(x);
}
__device__ __forceinline__ ushort f2bfu(float f) {
    __hip_bfloat16 b = __float2bfloat16(f);
    return *reinterpret_cast<ushort*>(&b);
}

// ------ kernel 1: fused normalize (both halves) + positive-pair sim ------
__global__ __launch_bounds__(256) void norm_pos_kernel(
        const float* __restrict__ z_i, const float* __restrict__ z_j,
        ushort* __restrict__ zn, float* __restrict__ sim_pos,
        float* __restrict__ denom) {
    const int wid = threadIdx.x >> 6, lane = threadIdx.x & 63;
    const int i = blockIdx.x * 4 + wid;  // 0..4095
    const float4 vi = *reinterpret_cast<const float4*>(z_i + (size_t)i * D + lane * 4);
    const float4 vj = *reinterpret_cast<const float4*>(z_j + (size_t)i * D + lane * 4);
    float ssi = vi.x * vi.x + vi.y * vi.y + vi.z * vi.z + vi.w * vi.w;
    float ssj = vj.x * vj.x + vj.y * vj.y + vj.z * vj.z + vj.w * vj.w;
    float dt  = vi.x * vj.x + vi.y * vj.y + vi.z * vj.z + vi.w * vj.w;
    #pragma unroll
    for (int off = 32; off; off >>= 1) {
        ssi += __shfl_xor(ssi, off);
        ssj += __shfl_xor(ssj, off);
        dt  += __shfl_xor(dt,  off);
    }
    const float ri = rsqrtf(ssi), rj = rsqrtf(ssj);
    ushort4 oi, oj;
    oi.x = f2bfu(vi.x * ri); oi.y = f2bfu(vi.y * ri);
    oi.z = f2bfu(vi.z * ri); oi.w = f2bfu(vi.w * ri);
    oj.x = f2bfu(vj.x * rj); oj.y = f2bfu(vj.y * rj);
    oj.z = f2bfu(vj.z * rj); oj.w = f2bfu(vj.w * rj);
    *reinterpret_cast<ushort4*>(zn + (size_t)i * D + lane * 4) = oi;
    *reinterpret_cast<ushort4*>(zn + (size_t)(i + NHALF) * D + lane * 4) = oj;
    if (lane == 0) {
        const float sp = dt * ri * rj * INV_T;
        sim_pos[i] = sp;
        sim_pos[i + NHALF] = sp;   // symmetric
        denom[i] = 0.0f;
        denom[i + NHALF] = 0.0f;
    }
}

// ------ kernel 2: fused symmetric sim-GEMM + exp + row/col sums ------
// BM=BN=128, BK=32, 4 waves (2x2), per-wave 64x64, mfma_f32_16x16x32_bf16.
// T4 counted-vmcnt 3-buffer ring (3 x (8+8) KB = 48 KB LDS, 3 blocks/CU):
//   prologue: STAGE(0), STAGE(1)            // 8 loads/thread in flight
//   iter ks:  s_waitcnt vmcnt(4)            // stage ks landed; ks+1 in flight
//             s_barrier                     // all waves: stage ks landed AND
//                                           //   all reads of buf[(ks-1)%3] done
//             STAGE(ks+2) -> buf[(ks+2)%3]  // == buf[(ks-1)%3], WAR-safe
//             ds_read buf[ks%3]; 16 x MFMA
// No vmcnt(0) drain in the main loop (T4). K-major slot layout
// (slot = kchunk*128 + row, 16B slots): conflict-free ds_read_b128
// (verified 0 conflicts in R3) + linear global_load_lds destinations.
// Grid: R2's exact 2D 64x64 with block-uniform early exit (A/B isolation:
// schedule is the only change vs the 47.5us R2 baseline).
__global__ __launch_bounds__(256) void gemm_denom_kernel(
        const ushort* __restrict__ zn, float* __restrict__ denom) {
    const int tr = blockIdx.x;
    const int tc = blockIdx.y;
    if (tc < tr) return;  // block-uniform exit before any sync

    __shared__ ushort As[3][4 * 128 * 8];  // 3 x 8 KB
    __shared__ ushort Bs[3][4 * 128 * 8];  // 3 x 8 KB

    const int tid  = threadIdx.x;
    const int lane = tid & 63;
    const int wid  = tid >> 6;
    const int wr   = wid >> 1;
    const int wc   = wid & 1;
    const int r16  = lane & 15;
    const int kgrp = lane >> 4;
    const int row0 = tr * 128;
    const int col0 = tc * 128;

    // per-thread staging slots: s = it*256+tid, kchunk = s>>7, row = s&127
    const int s0 = tid, s1 = 256 + tid;
    const int r0s = s0 & 127, c0s = (s0 >> 7) * 8;
    const int r1s = s1 & 127, c1s = (s1 >> 7) * 8;
    const ushort* gA0 = zn + (size_t)(row0 + r0s) * D + c0s;
    const ushort* gA1 = zn + (size_t)(row0 + r1s) * D + c1s;
    const ushort* gB0 = zn + (size_t)(col0 + r0s) * D + c0s;
    const ushort* gB1 = zn + (size_t)(col0 + r1s) * D + c1s;
    const int d0 = (0 * 256 + wid * 64) * 8;   // LDS dest offsets (ushort units)
    const int d1 = (1 * 256 + wid * 64) * 8;

    #define STAGE(buf, k0)                                                        \
        do {                                                                      \
            __builtin_amdgcn_global_load_lds((const AS1 void*)(gA0 + (k0)),       \
                (AS3 void*)(As[buf] + d0), 16, 0, 0);                             \
            __builtin_amdgcn_global_load_lds((const AS1 void*)(gA1 + (k0)),       \
                (AS3 void*)(As[buf] + d1), 16, 0, 0);                             \
            __builtin_amdgcn_global_load_lds((const AS1 void*)(gB0 + (k0)),       \
                (AS3 void*)(Bs[buf] + d0), 16, 0, 0);                             \
            __builtin_amdgcn_global_load_lds((const AS1 void*)(gB1 + (k0)),       \
                (AS3 void*)(Bs[buf] + d1), 16, 0, 0);                             \
        } while (0)

    f32x4 acc[4][4];
    #pragma unroll
    for (int m = 0; m < 4; ++m)
        #pragma unroll
        for (int n = 0; n < 4; ++n) {
            f32x4 z = {0.f, 0.f, 0.f, 0.f};
            acc[m][n] = z;
        }

    STAGE(0, 0);
    STAGE(1, 32);

    #pragma unroll
    for (int ks = 0; ks < 8; ++ks) {
        const int cur = ks % 3;
        // counted wait: oldest stage (ks) landed; newer stays in flight
        if (ks < 7) asm volatile("s_waitcnt vmcnt(4)" ::: "memory");
        else        asm volatile("s_waitcnt vmcnt(0)" ::: "memory");
        __builtin_amdgcn_s_barrier();
        asm volatile("" ::: "memory");  // pin: no loads migrate above barrier
        if (ks < 6) STAGE((ks + 2) % 3, (ks + 2) * 32);
        short8 a[4], b[4];
        #pragma unroll
        for (int m = 0; m < 4; ++m)
            a[m] = *reinterpret_cast<const short8*>(
                As[cur] + ((kgrp * 128) + wr * 64 + m * 16 + r16) * 8);
        #pragma unroll
        for (int n = 0; n < 4; ++n)
            b[n] = *reinterpret_cast<const short8*>(
                Bs[cur] + ((kgrp * 128) + wc * 64 + n * 16 + r16) * 8);
        #pragma unroll
        for (int m = 0; m < 4; ++m)
            #pragma unroll
            for (int n = 0; n < 4; ++n)
                acc[m][n] = __builtin_amdgcn_mfma_f32_16x16x32_bf16(
                    a[m], b[n], acc[m][n], 0, 0, 0);
    }
    #undef STAGE

    // ---- epilogue: exp, diag zero, row sums (+ col sums if off-diagonal) ----
    const bool offdiag = (tr != tc);
    float cs[4] = {0.f, 0.f, 0.f, 0.f};
    #pragma unroll
    for (int m = 0; m < 4; ++m) {
        #pragma unroll
        for (int reg = 0; reg < 4; ++reg) {
            const int rg = row0 + wr * 64 + m * 16 + kgrp * 4 + reg;
            float rs = 0.f;
            #pragma unroll
            for (int n = 0; n < 4; ++n) {
                const int cg = col0 + wc * 64 + n * 16 + r16;
                float e = __expf(acc[m][n][reg] * INV_T);
                if (rg == cg) e = 0.f;   // only possible when tr==tc
                rs += e;
                cs[n] += e;
            }
            rs += __shfl_xor(rs, 1);
            rs += __shfl_xor(rs, 2);
            rs += __shfl_xor(rs, 4);
            rs += __shfl_xor(rs, 8);
            if (r16 == 0) atomicAdd(&denom[rg], rs);
        }
    }
    if (offdiag) {
        #pragma unroll
        for (int n = 0; n < 4; ++n) {
            cs[n] += __shfl_xor(cs[n], 16);
            cs[n] += __shfl_xor(cs[n], 32);
        }
        if (kgrp == 0) {
            #pragma unroll
            for (int n = 0; n < 4; ++n)
                atomicAdd(&denom[col0 + wc * 64 + n * 16 + r16], cs[n]);
        }
    }
}

// ---------------- kernel 3: final loss reduction ----------------
__global__ __launch_bounds__(1024) void final_kernel(
        const float* __restrict__ sim_pos, const float* __restrict__ denom,
        float* __restrict__ out) {
    const int tid = threadIdx.x;
    float s = 0.f;
    for (int i = tid; i < TWO_N; i += 1024)
        s += sim_pos[i] - logf(denom[i]);
    #pragma unroll
    for (int off = 32; off; off >>= 1) s += __shfl_down(s, off);
    __shared__ float red[16];
    const int wid = tid >> 6, lane = tid & 63;
    if (lane == 0) red[wid] = s;
    __syncthreads();
    if (tid == 0) {
        float t = 0.f;
        #pragma unroll
        for (int w = 0; w < 16; ++w) t += red[w];
        out[0] = -t / (float)TWO_N;
    }
}

extern "C" void kernel_launch(void* const* d_in, const int* in_sizes, int n_in,
                              void* d_out, int out_size, void* d_ws, size_t ws_size,
                              hipStream_t stream) {
    const float* z_i = (const float*)d_in[0];
    const float* z_j = (const float*)d_in[1];
    float* out = (float*)d_out;

    ushort* zn      = (ushort*)d_ws;                                  // 4 MB
    float*  sim_pos = (float*)((char*)d_ws + (size_t)TWO_N * D * 2);  // 32 KB
    float*  denom   = sim_pos + TWO_N;                                // 32 KB

    norm_pos_kernel<<<NHALF / 4, 256, 0, stream>>>(z_i, z_j, zn, sim_pos, denom);
    dim3 grid(NTILE, NTILE);
    gemm_denom_kernel<<<grid, 256, 0, stream>>>(zn, denom);
    final_kernel<<<1, 1024, 0, stream>>>(sim_pos, denom, out);
}

// Round 7
// 54.627 us; speedup vs baseline: 1.6406x; 1.4802x over previous
//
#include <hip/hip_runtime.h>
#include <hip/hip_bf16.h>

#define TWO_N 8192
#define NHALF 4096
#define D 256
#define NTILE 64            // 8192 / 128 tiles per dimension
#define BLK_ELEMS 32768     // 32 kchunks * 128 rows * 8 elems per 128-row block
static constexpr float INV_T = 2.0f; // 1 / 0.5

typedef __attribute__((ext_vector_type(8))) short short8;
typedef __attribute__((ext_vector_type(4))) float f32x4;

#define AS1 __attribute__((address_space(1)))
#define AS3 __attribute__((address_space(3)))

__device__ __forceinline__ ushort f2bfu(float f) {
    __hip_bfloat16 b = __float2bfloat16(f);
    return *reinterpret_cast<ushort*>(&b);
}

// ------ kernel 1: fused normalize + positive-pair sim, blocked-K-major out --
// znb layout: [rowblock(64)][kchunk(32)][row-in-block(128)][elem(8)]
//   flat = ((row>>7)*32 + (col>>3))*1024 + (row&127)*8 + (col&7)
// This makes each (tile, K-step) of the GEMM a contiguous 8 KB region ->
// global_load_lds staging is fully coalesced with linear LDS dests, AND the
// LDS image is the conflict-free K-major layout (0 conflicts, verified R3).
__global__ __launch_bounds__(256) void norm_pos_kernel(
        const float* __restrict__ z_i, const float* __restrict__ z_j,
        ushort* __restrict__ znb, float* __restrict__ sim_pos,
        float* __restrict__ denom) {
    const int wid = threadIdx.x >> 6, lane = threadIdx.x & 63;
    const int i = blockIdx.x * 4 + wid;  // 0..4095
    const float4 vi = *reinterpret_cast<const float4*>(z_i + (size_t)i * D + lane * 4);
    const float4 vj = *reinterpret_cast<const float4*>(z_j + (size_t)i * D + lane * 4);
    float ssi = vi.x * vi.x + vi.y * vi.y + vi.z * vi.z + vi.w * vi.w;
    float ssj = vj.x * vj.x + vj.y * vj.y + vj.z * vj.z + vj.w * vj.w;
    float dt  = vi.x * vj.x + vi.y * vj.y + vi.z * vj.z + vi.w * vj.w;
    #pragma unroll
    for (int off = 32; off; off >>= 1) {
        ssi += __shfl_xor(ssi, off);
        ssj += __shfl_xor(ssj, off);
        dt  += __shfl_xor(dt,  off);
    }
    const float ri = rsqrtf(ssi), rj = rsqrtf(ssj);
    ushort4 oi, oj;
    oi.x = f2bfu(vi.x * ri); oi.y = f2bfu(vi.y * ri);
    oi.z = f2bfu(vi.z * ri); oi.w = f2bfu(vi.w * ri);
    oj.x = f2bfu(vj.x * rj); oj.y = f2bfu(vj.y * rj);
    oj.z = f2bfu(vj.z * rj); oj.w = f2bfu(vj.w * rj);
    // cols lane*4..lane*4+3: kchunk = lane>>1, e = (lane&1)*4
    const int c = lane >> 1, e = (lane & 1) * 4;
    const int i2 = i + NHALF;
    const size_t bi = ((size_t)(i  >> 7) * 32 + c) * 1024 + (i  & 127) * 8 + e;
    const size_t bj = ((size_t)(i2 >> 7) * 32 + c) * 1024 + (i2 & 127) * 8 + e;
    *reinterpret_cast<ushort4*>(znb + bi) = oi;
    *reinterpret_cast<ushort4*>(znb + bj) = oj;
    if (lane == 0) {
        const float sp = dt * ri * rj * INV_T;
        sim_pos[i] = sp;
        sim_pos[i + NHALF] = sp;   // symmetric
        denom[i] = 0.0f;
        denom[i + NHALF] = 0.0f;
    }
}

// ------ kernel 2: fused symmetric sim-GEMM + exp + row/col sums ------
// BM=BN=128, BK=32, 4 waves (2x2), per-wave 64x64, mfma_f32_16x16x32_bf16.
// T4 counted-vmcnt 3-buffer ring (48 KB LDS): no vmcnt(0) in the main loop.
// Staging source = contiguous 8 KB per tile/K-step (blocked layout) ->
// fully coalesced; LDS image = K-major, conflict-free ds_read_b128.
__global__ __launch_bounds__(256) void gemm_denom_kernel(
        const ushort* __restrict__ znb, float* __restrict__ denom) {
    const int tr = blockIdx.x;
    const int tc = blockIdx.y;
    if (tc < tr) return;  // block-uniform exit before any sync

    __shared__ ushort As[3][4 * 128 * 8];  // 3 x 8 KB
    __shared__ ushort Bs[3][4 * 128 * 8];  // 3 x 8 KB

    const int tid  = threadIdx.x;
    const int lane = tid & 63;
    const int wid  = tid >> 6;
    const int wr   = wid >> 1;
    const int wc   = wid & 1;
    const int r16  = lane & 15;
    const int kgrp = lane >> 4;
    const int row0 = tr * 128;
    const int col0 = tc * 128;

    // staging: chunk q (16B) of the contiguous 8KB K-step region; dest slot q.
    // per thread: q0 = tid, q1 = 256 + tid.
    const ushort* gA = znb + (size_t)tr * BLK_ELEMS + tid * 8;
    const ushort* gB = znb + (size_t)tc * BLK_ELEMS + tid * 8;
    const int d0 = (0 * 256 + wid * 64) * 8;   // wave-uniform LDS dest (ushorts)
    const int d1 = (1 * 256 + wid * 64) * 8;

    #define STAGE(buf, koff)                                                      \
        do {                                                                      \
            __builtin_amdgcn_global_load_lds((const AS1 void*)(gA + (koff)),      \
                (AS3 void*)(As[buf] + d0), 16, 0, 0);                             \
            __builtin_amdgcn_global_load_lds((const AS1 void*)(gA + (koff) + 2048),\
                (AS3 void*)(As[buf] + d1), 16, 0, 0);                             \
            __builtin_amdgcn_global_load_lds((const AS1 void*)(gB + (koff)),      \
                (AS3 void*)(Bs[buf] + d0), 16, 0, 0);                             \
            __builtin_amdgcn_global_load_lds((const AS1 void*)(gB + (koff) + 2048),\
                (AS3 void*)(Bs[buf] + d1), 16, 0, 0);                             \
        } while (0)

    f32x4 acc[4][4];
    #pragma unroll
    for (int m = 0; m < 4; ++m)
        #pragma unroll
        for (int n = 0; n < 4; ++n) {
            f32x4 z = {0.f, 0.f, 0.f, 0.f};
            acc[m][n] = z;
        }

    STAGE(0, 0);
    STAGE(1, 4096);

    #pragma unroll
    for (int ks = 0; ks < 8; ++ks) {
        const int cur = ks % 3;
        // counted wait: oldest stage (ks) landed; newer stays in flight (T4)
        if (ks < 7) asm volatile("s_waitcnt vmcnt(4)" ::: "memory");
        else        asm volatile("s_waitcnt vmcnt(0)" ::: "memory");
        __builtin_amdgcn_s_barrier();
        asm volatile("" ::: "memory");  // pin: no loads migrate above barrier
        if (ks < 6) STAGE((ks + 2) % 3, (ks + 2) * 4096);
        short8 a[4], b[4];
        #pragma unroll
        for (int m = 0; m < 4; ++m)
            a[m] = *reinterpret_cast<const short8*>(
                As[cur] + ((kgrp * 128) + wr * 64 + m * 16 + r16) * 8);
        #pragma unroll
        for (int n = 0; n < 4; ++n)
            b[n] = *reinterpret_cast<const short8*>(
                Bs[cur] + ((kgrp * 128) + wc * 64 + n * 16 + r16) * 8);
        #pragma unroll
        for (int m = 0; m < 4; ++m)
            #pragma unroll
            for (int n = 0; n < 4; ++n)
                acc[m][n] = __builtin_amdgcn_mfma_f32_16x16x32_bf16(
                    a[m], b[n], acc[m][n], 0, 0, 0);
    }
    #undef STAGE

    // ---- epilogue: exp, diag zero, row sums (+ col sums if off-diagonal) ----
    const bool offdiag = (tr != tc);
    float cs[4] = {0.f, 0.f, 0.f, 0.f};
    #pragma unroll
    for (int m = 0; m < 4; ++m) {
        #pragma unroll
        for (int reg = 0; reg < 4; ++reg) {
            const int rg = row0 + wr * 64 + m * 16 + kgrp * 4 + reg;
            float rs = 0.f;
            #pragma unroll
            for (int n = 0; n < 4; ++n) {
                const int cg = col0 + wc * 64 + n * 16 + r16;
                float e = __expf(acc[m][n][reg] * INV_T);
                if (rg == cg) e = 0.f;   // only possible when tr==tc
                rs += e;
                cs[n] += e;
            }
            rs += __shfl_xor(rs, 1);
            rs += __shfl_xor(rs, 2);
            rs += __shfl_xor(rs, 4);
            rs += __shfl_xor(rs, 8);
            if (r16 == 0) atomicAdd(&denom[rg], rs);
        }
    }
    if (offdiag) {
        #pragma unroll
        for (int n = 0; n < 4; ++n) {
            cs[n] += __shfl_xor(cs[n], 16);
            cs[n] += __shfl_xor(cs[n], 32);
        }
        if (kgrp == 0) {
            #pragma unroll
            for (int n = 0; n < 4; ++n)
                atomicAdd(&denom[col0 + wc * 64 + n * 16 + r16], cs[n]);
        }
    }
}

// ---------------- kernel 3: final loss reduction ----------------
__global__ __launch_bounds__(1024) void final_kernel(
        const float* __restrict__ sim_pos, const float* __restrict__ denom,
        float* __restrict__ out) {
    const int tid = threadIdx.x;
    float s = 0.f;
    for (int i = tid; i < TWO_N; i += 1024)
        s += sim_pos[i] - logf(denom[i]);
    #pragma unroll
    for (int off = 32; off; off >>= 1) s += __shfl_down(s, off);
    __shared__ float red[16];
    const int wid = tid >> 6, lane = tid & 63;
    if (lane == 0) red[wid] = s;
    __syncthreads();
    if (tid == 0) {
        float t = 0.f;
        #pragma unroll
        for (int w = 0; w < 16; ++w) t += red[w];
        out[0] = -t / (float)TWO_N;
    }
}

extern "C" void kernel_launch(void* const* d_in, const int* in_sizes, int n_in,
                              void* d_out, int out_size, void* d_ws, size_t ws_size,
                              hipStream_t stream) {
    const float* z_i = (const float*)d_in[0];
    const float* z_j = (const float*)d_in[1];
    float* out = (float*)d_out;

    ushort* znb     = (ushort*)d_ws;                                  // 4 MB
    float*  sim_pos = (float*)((char*)d_ws + (size_t)TWO_N * D * 2);  // 32 KB
    float*  denom   = sim_pos + TWO_N;                                // 32 KB

    norm_pos_kernel<<<NHALF / 4, 256, 0, stream>>>(z_i, z_j, znb, sim_pos, denom);
    dim3 grid(NTILE, NTILE);
    gemm_denom_kernel<<<grid, 256, 0, stream>>>(znb, denom);
    final_kernel<<<1, 1024, 0, stream>>>(sim_pos, denom, out);
}